// Round 15
// baseline (418.612 us; speedup 1.0000x reference)
//
#include <hip/hip_runtime.h>

// MoE top-2/8: routed bf16-MFMA grouped GEMMs.
// R15: R14 with the gemm1 grid fixed (x = HID/64 = 32, was 64 -> OOB crash).
// m97-style 2-phase GEMMs: 128x128 tile, BK=32, 4 waves, dbuf 32KB LDS,
// launch_bounds(256,3) => 3 blocks/CU.

#define N_TOK 8192
#define DIM   1024
#define HID   2048
#define NEXP  8
#define NK    (N_TOK * 2)
#define MAXT1 136   // max 128-row tiles (128 full + 8 partial)
#define G1Y   272   // gemm1 y: [0,136) tiles, [136,264) W2T, [264,272) zero

typedef __attribute__((ext_vector_type(8))) short short8;
typedef __attribute__((ext_vector_type(4))) float f32x4;

#define BARX() __builtin_amdgcn_s_barrier()
#define FEN()  asm volatile("" ::: "memory")
#define VMW0() asm volatile("s_waitcnt vmcnt(0)" ::: "memory")
#define PRIO(p) __builtin_amdgcn_s_setprio(p)

static __device__ __forceinline__ unsigned short f2bf(float f) {
  unsigned int u = __float_as_uint(f);
  u += 0x7fffu + ((u >> 16) & 1u);
  return (unsigned short)(u >> 16);
}

static __device__ __forceinline__ void glds16(const void* g, void* l) {
  __builtin_amdgcn_global_load_lds(
      (const __attribute__((address_space(1))) unsigned int*)g,
      (__attribute__((address_space(3))) unsigned int*)l, 16, 0, 0);
}

// ---- 64x64 transpose-convert tile (256 threads) ----
__device__ __forceinline__ void transpose_tile(const float* __restrict__ s,
                                               unsigned short* __restrict__ d,
                                               int R, int C, int c0, int r0,
                                               unsigned short (*tT)[68]) {
  int tid = threadIdx.x;
  int c = tid & 63, rq = tid >> 6;
#pragma unroll
  for (int q = 0; q < 4; ++q) {
    int rb = q * 16 + rq * 4;
    ushort4 v;
    v.x = f2bf(s[(size_t)(r0 + rb + 0) * C + c0 + c]);
    v.y = f2bf(s[(size_t)(r0 + rb + 1) * C + c0 + c]);
    v.z = f2bf(s[(size_t)(r0 + rb + 2) * C + c0 + c]);
    v.w = f2bf(s[(size_t)(r0 + rb + 3) * C + c0 + c]);
    *(ushort4*)&tT[c][rb] = v;
  }
  __syncthreads();
#pragma unroll
  for (int it = 0; it < 4; ++it) {
    int idx = it * 256 + tid;
    int cc = idx >> 4;
    int r4 = (idx & 15) * 4;
    *(ushort4*)(d + (size_t)(c0 + cc) * R + r0 + r4) = *(const ushort4*)&tT[cc][r4];
  }
}

// ================= prep: W1^T || router (+x->bf16) ================
__global__ __launch_bounds__(256) void prep_k(
    const float* __restrict__ x, const float* __restrict__ Wr,
    const float* __restrict__ W1,
    unsigned short* __restrict__ w1t,
    unsigned short* __restrict__ xb, int* __restrict__ te,
    float* __restrict__ tg) {
  __shared__ unsigned short tT[64][68];
  int bid = blockIdx.x;
  if (bid < 8192) {                       // W1 transpose
    int z = bid >> 10, rem = bid & 1023;
    int c0 = (rem & 63) * 64, r0 = (rem >> 6) * 64;
    transpose_tile(W1 + (size_t)z * DIM * 2 * HID,
                   w1t + (size_t)z * DIM * 2 * HID, DIM, 2 * HID, c0, r0, tT);
  } else {                                // router (4 tokens, 1 wave each)
    int n = (bid - 8192) * 4 + (threadIdx.x >> 6);
    int lane = threadIdx.x & 63;
    float z[8];
#pragma unroll
    for (int e = 0; e < 8; ++e) z[e] = 0.f;
    const float* xr = x + (size_t)n * DIM;
    unsigned short* xbr = xb + (size_t)n * DIM;
#pragma unroll 4
    for (int i = 0; i < DIM / 64; ++i) {
      int d = lane + i * 64;
      float xv = xr[d];
      xbr[d] = f2bf(xv);
      float4 w0 = *(const float4*)(Wr + (size_t)d * 8);
      float4 w1 = *(const float4*)(Wr + (size_t)d * 8 + 4);
      z[0] += xv * w0.x; z[1] += xv * w0.y; z[2] += xv * w0.z; z[3] += xv * w0.w;
      z[4] += xv * w1.x; z[5] += xv * w1.y; z[6] += xv * w1.z; z[7] += xv * w1.w;
    }
    for (int off = 32; off; off >>= 1)
#pragma unroll
      for (int e = 0; e < 8; ++e) z[e] += __shfl_down(z[e], off);
    if (lane == 0) {
      int e0 = 0; float v0 = z[0];
#pragma unroll
      for (int e = 1; e < 8; ++e) if (z[e] > v0) { v0 = z[e]; e0 = e; }
      int e1 = -1; float v1 = -3.4e38f;
#pragma unroll
      for (int e = 0; e < 8; ++e) if (e != e0 && z[e] > v1) { v1 = z[e]; e1 = e; }
      float r = expf(v1 - v0);
      float s0 = 1.f / (1.f + r);
      te[n * 2] = e0; te[n * 2 + 1] = e1;
      tg[n * 2] = s0; tg[n * 2 + 1] = r * s0;
    }
  }
}

// ===== sortscan: one block; histogram -> offs/tl128, scatter ==========
__global__ __launch_bounds__(1024) void sortscan_k(
    const int* __restrict__ te, const float* __restrict__ tg,
    int* __restrict__ offs, int* __restrict__ tl128,
    int* __restrict__ rows, float* __restrict__ rowg) {
  __shared__ int hist[8];
  __shared__ int curs[8];
  int tid = threadIdx.x;
  if (tid < 8) hist[tid] = 0;
  __syncthreads();
  for (int i = tid; i < NK; i += 1024) atomicAdd(&hist[te[i]], 1);
  __syncthreads();
  if (tid == 0) {
    int o = 0, t1 = 0;
    offs[0] = 0; tl128[0] = 0;
    for (int e = 0; e < NEXP; ++e) {
      curs[e] = o;
      o += hist[e];
      offs[e + 1] = o;
      t1 += (hist[e] + 127) >> 7;
      tl128[e + 1] = t1;
    }
  }
  __syncthreads();
  for (int i = tid; i < NK; i += 1024) {
    int e = te[i];
    int pos = atomicAdd(&curs[e], 1);
    rows[pos] = i >> 1;
    rowg[pos] = tg[i];
  }
}

// ============ 2-phase 128x128 grouped GEMM, BK=32, 3 blocks/CU ==============
// 4 waves (wr=w>>1, wc=w&1): wave out = rows [wr*64,+64) x B-rows [wc*64,+64).
// GID0 covers 64 hcols/block (jb in [0, HID/64)): B-row rB -> wcb=rB>>6,
// u=rB&63, hcol=j0+wcb*32+(u&31), +HID if u>=32 (b-half).
// Per K-step: stage(t+1 -> buf^1) | read a[4],b[4] | 16 MFMA | vmcnt(0)|bar.
template <int GID>
__global__ __launch_bounds__(256, 3) void moe_gemm2p(
    const unsigned short* __restrict__ Asrc,
    const unsigned short* __restrict__ Wt,
    const float* __restrict__ bias,
    unsigned short* __restrict__ hb,
    float* __restrict__ out,
    const int* __restrict__ rows,
    const float* __restrict__ rowg,
    const int* __restrict__ offs,
    const int* __restrict__ tl,
    const float* __restrict__ W2f,       // GID0 aux
    unsigned short* __restrict__ w2td,   // GID0 aux
    float* __restrict__ outz) {          // GID0 aux
  constexpr int KD = (GID == 0) ? DIM : HID;
  constexpr int NT = KD / 32;
  // elements: A buf0 [0,4096), A buf1 [4096,8192), B buf0 [8192,..), B buf1
  __shared__ unsigned short smem[16384];

  int bt = blockIdx.y;
  if (GID == 0 && bt >= MAXT1) {
    if (bt < MAXT1 + 128) {              // W2 transpose, 1 tile/block
      int t = (bt - MAXT1) * 32 + (int)blockIdx.x;   // 0..4095 (gridDim.x=32)
      int z = t >> 9, rem = t & 511;
      int c0 = (rem & 15) * 64, r0 = (rem >> 4) * 64;
      transpose_tile(W2f + (size_t)z * HID * DIM,
                     w2td + (size_t)z * HID * DIM, HID, DIM, c0, r0,
                     (unsigned short(*)[68])smem);
    } else {                             // zero out
      int t = (bt - MAXT1 - 128) * 32 + (int)blockIdx.x;  // 0..255
      float4* o4 = (float4*)outz;
      int idx = t * 256 + threadIdx.x;
#pragma unroll
      for (int i = 0; i < 32; ++i) o4[idx + i * 65536] = (float4){0.f, 0.f, 0.f, 0.f};
    }
    return;
  }
  if (bt >= tl[NEXP]) return;
  int e = 0;
  while (e < NEXP - 1 && bt >= tl[e + 1]) ++e;
  int rt = bt - tl[e];
  int base = offs[e];
  int cntE = offs[e + 1] - base;
  int row0 = rt * 128;
  int jb = blockIdx.x;

  int tid = threadIdx.x, lane = tid & 63, w = tid >> 6;
  int wr = w >> 1, wc = w & 1;

  // ---------- staging (R10 BK=32 swizzle: src granule, linear LDS) ----------
  int g8 = (((lane & 3) ^ ((lane >> 3) & 3)) * 8);
  const unsigned short* aP[2];
  const unsigned short* bP[2];
  int aD[2], bD[2];
#pragma unroll
  for (int s = 0; s < 2; ++s) {
    int rA = w * 16 + (lane >> 2) + s * 64;
    int rr = row0 + rA; rr = rr < cntE ? rr : cntE - 1;
    if (GID == 0) {
      int tok = rows[base + rr];
      aP[s] = Asrc + (size_t)tok * DIM + g8;
    } else {
      aP[s] = Asrc + (size_t)(base + rr) * HID + g8;
    }
    aD[s] = (w * 16 + s * 64) * 32;
    int rB = w * 16 + (lane >> 2) + s * 64;
    if (GID == 0) {
      int j0 = jb * 64;
      int u = rB & 63, wcb = rB >> 6;
      int hcol = j0 + wcb * 32 + (u & 31);
      int w1row = hcol + (u >> 5) * HID;       // +HID for b-half of swiGLU
      bP[s] = Wt + ((size_t)e * 2 * HID + w1row) * DIM + g8;
    } else {
      bP[s] = Wt + ((size_t)e * DIM + (jb * 128 + rB)) * HID + g8;
    }
    bD[s] = (w * 16 + s * 64) * 32;
  }

  auto stg = [&](int t, int nxt) {
    if (t < NT) {
      glds16(aP[0] + (size_t)t * 32, smem + nxt * 4096 + aD[0]);
      glds16(aP[1] + (size_t)t * 32, smem + nxt * 4096 + aD[1]);
      glds16(bP[0] + (size_t)t * 32, smem + 8192 + nxt * 4096 + bD[0]);
      glds16(bP[1] + (size_t)t * 32, smem + 8192 + nxt * 4096 + bD[1]);
    }
  };

  // ---------- ds_read offsets (R10 swizzle: slot = kg ^ ((r>>1)&3)) ----------
  int kg = lane >> 4, coll = lane & 15;
  int koff = ((kg ^ ((lane >> 1) & 3)) * 8);
  unsigned aoff[4], boff[4];
#pragma unroll
  for (int m = 0; m < 4; ++m) aoff[m] = (unsigned)((wr * 64 + m * 16 + coll) * 32 + koff);
#pragma unroll
  for (int n = 0; n < 4; ++n) boff[n] = (unsigned)((wc * 64 + n * 16 + coll) * 32 + koff);

  f32x4 acc[4][4];
#pragma unroll
  for (int m = 0; m < 4; ++m)
#pragma unroll
    for (int n = 0; n < 4; ++n) acc[m][n] = (f32x4){0.f, 0.f, 0.f, 0.f};

  short8 a[4], b[4];

  // ---------- prologue ----------
  stg(0, 0);
  VMW0(); FEN(); BARX(); FEN();

  int cur = 0;
  for (int t = 0; t < NT; ++t) {
    stg(t + 1, cur ^ 1);
#pragma unroll
    for (int m = 0; m < 4; ++m)
      a[m] = *(const short8*)(smem + cur * 4096 + aoff[m]);
#pragma unroll
    for (int n = 0; n < 4; ++n)
      b[n] = *(const short8*)(smem + 8192 + cur * 4096 + boff[n]);
    PRIO(1);
#pragma unroll
    for (int m = 0; m < 4; ++m)
#pragma unroll
      for (int n = 0; n < 4; ++n)
        acc[m][n] = __builtin_amdgcn_mfma_f32_16x16x32_bf16(a[m], b[n], acc[m][n], 0, 0, 0);
    PRIO(0);
    VMW0(); FEN(); BARX(); FEN();
    cur ^= 1;
  }

  // ---------- epilogue ----------
  int rowl = lane >> 4;
  if (GID == 0) {
    int j0 = jb * 64;
#pragma unroll
    for (int n = 0; n < 2; ++n) {
      int hcol = j0 + wc * 32 + n * 16 + coll;
      float ba = bias[e * 2 * HID + hcol];
      float bb = bias[e * 2 * HID + HID + hcol];
#pragma unroll
      for (int m = 0; m < 4; ++m)
#pragma unroll
        for (int j = 0; j < 4; ++j) {
          int grow = row0 + wr * 64 + m * 16 + rowl * 4 + j;
          if (grow < cntE) {
            float av = acc[m][n][j] + ba;
            float bv = acc[m][n + 2][j] + bb;
            float hv = av / (1.f + __expf(-av)) * bv;
            hb[(size_t)(base + grow) * HID + hcol] = f2bf(hv);
          }
        }
    }
  } else {
#pragma unroll
    for (int m = 0; m < 4; ++m)
#pragma unroll
      for (int j = 0; j < 4; ++j) {
        int grow = row0 + wr * 64 + m * 16 + rowl * 4 + j;
        if (grow < cntE) {
          int tok = rows[base + grow];
          float g = rowg[base + grow];
#pragma unroll
          for (int n = 0; n < 4; ++n) {
            int col = jb * 128 + wc * 64 + n * 16 + coll;
            atomicAdd(&out[(size_t)tok * DIM + col],
                      g * (acc[m][n][j] + bias[e * DIM + col]));
          }
        }
      }
  }
}

extern "C" void kernel_launch(void* const* d_in, const int* in_sizes, int n_in,
                              void* d_out, int out_size, void* d_ws, size_t ws_size,
                              hipStream_t stream) {
  (void)in_sizes; (void)n_in; (void)out_size;
  const float* x  = (const float*)d_in[0];
  const float* Wr = (const float*)d_in[1];
  const float* W1 = (const float*)d_in[2];
  const float* b1 = (const float*)d_in[3];
  const float* W2 = (const float*)d_in[4];
  const float* b2 = (const float*)d_in[5];
  float* out = (float*)d_out;
  char* ws = (char*)d_ws;

  const size_t o_xb   = 0;
  const size_t o_w1t  = o_xb   + (size_t)N_TOK * DIM * 2;
  const size_t o_w2t  = o_w1t  + (size_t)NEXP * 2 * HID * DIM * 2;
  const size_t o_hb   = o_w2t  + (size_t)NEXP * DIM * HID * 2;
  const size_t o_rows = o_hb   + (size_t)NK * HID * 2;
  const size_t o_rowg = o_rows + (size_t)NK * 4;
  const size_t o_te   = o_rowg + (size_t)NK * 4;
  const size_t o_tg   = o_te   + (size_t)NK * 4;
  const size_t o_offs = o_tg   + (size_t)NK * 4;
  const size_t o_t1   = o_offs + 64;
  const size_t need   = o_t1   + 64;
  if (ws_size < need) return;

  unsigned short* xb  = (unsigned short*)(ws + o_xb);
  unsigned short* w1t = (unsigned short*)(ws + o_w1t);
  unsigned short* w2t = (unsigned short*)(ws + o_w2t);
  unsigned short* hb  = (unsigned short*)(ws + o_hb);
  int*   rows = (int*)(ws + o_rows);
  float* rowg = (float*)(ws + o_rowg);
  int*   te   = (int*)(ws + o_te);
  float* tg   = (float*)(ws + o_tg);
  int*   offs = (int*)(ws + o_offs);
  int*   tl128 = (int*)(ws + o_t1);

  prep_k<<<10240, 256, 0, stream>>>(x, Wr, W1, w1t, xb, te, tg);
  sortscan_k<<<1, 1024, 0, stream>>>(te, tg, offs, tl128, rows, rowg);
  moe_gemm2p<0><<<dim3(HID / 64, G1Y), 256, 0, stream>>>(
      xb, w1t, b1, hb, nullptr, rows, rowg, offs, tl128, W2, w2t, out);
  moe_gemm2p<1><<<dim3(DIM / 128, MAXT1), 256, 0, stream>>>(
      hb, w2t, b2, nullptr, out, rows, rowg, offs, tl128, nullptr, nullptr, nullptr);
}

// Round 16
// 403.132 us; speedup vs baseline: 1.0384x; 1.0384x over previous
//
#include <hip/hip_runtime.h>

// MoE top-2/8: routed bf16-MFMA grouped GEMMs.
// R16: triple-buffered 2-phase 128x128 GEMM, BK=32, counted vmcnt(4) (one
// full K-step of prefetch slack), one barrier/K-step, 48KB LDS, 3 blocks/CU.
// Fixes R15's zero-depth pipeline (vmcnt(0) drain every step).

#define N_TOK 8192
#define DIM   1024
#define HID   2048
#define NEXP  8
#define NK    (N_TOK * 2)
#define MAXT1 136   // max 128-row tiles (128 full + 8 partial)
#define G1Y   272   // gemm1 y: [0,136) tiles, [136,264) W2T, [264,272) zero

typedef __attribute__((ext_vector_type(8))) short short8;
typedef __attribute__((ext_vector_type(4))) float f32x4;

#define BARX() __builtin_amdgcn_s_barrier()
#define FEN()  asm volatile("" ::: "memory")
#define VMW4() asm volatile("s_waitcnt vmcnt(4)" ::: "memory")
#define VMW0() asm volatile("s_waitcnt vmcnt(0)" ::: "memory")
#define PRIO(p) __builtin_amdgcn_s_setprio(p)

static __device__ __forceinline__ unsigned short f2bf(float f) {
  unsigned int u = __float_as_uint(f);
  u += 0x7fffu + ((u >> 16) & 1u);
  return (unsigned short)(u >> 16);
}

static __device__ __forceinline__ void glds16(const void* g, void* l) {
  __builtin_amdgcn_global_load_lds(
      (const __attribute__((address_space(1))) unsigned int*)g,
      (__attribute__((address_space(3))) unsigned int*)l, 16, 0, 0);
}

// ---- 64x64 transpose-convert tile (256 threads) ----
__device__ __forceinline__ void transpose_tile(const float* __restrict__ s,
                                               unsigned short* __restrict__ d,
                                               int R, int C, int c0, int r0,
                                               unsigned short (*tT)[68]) {
  int tid = threadIdx.x;
  int c = tid & 63, rq = tid >> 6;
#pragma unroll
  for (int q = 0; q < 4; ++q) {
    int rb = q * 16 + rq * 4;
    ushort4 v;
    v.x = f2bf(s[(size_t)(r0 + rb + 0) * C + c0 + c]);
    v.y = f2bf(s[(size_t)(r0 + rb + 1) * C + c0 + c]);
    v.z = f2bf(s[(size_t)(r0 + rb + 2) * C + c0 + c]);
    v.w = f2bf(s[(size_t)(r0 + rb + 3) * C + c0 + c]);
    *(ushort4*)&tT[c][rb] = v;
  }
  __syncthreads();
#pragma unroll
  for (int it = 0; it < 4; ++it) {
    int idx = it * 256 + tid;
    int cc = idx >> 4;
    int r4 = (idx & 15) * 4;
    *(ushort4*)(d + (size_t)(c0 + cc) * R + r0 + r4) = *(const ushort4*)&tT[cc][r4];
  }
}

// ================= prep: W1^T || router (+x->bf16) ================
__global__ __launch_bounds__(256) void prep_k(
    const float* __restrict__ x, const float* __restrict__ Wr,
    const float* __restrict__ W1,
    unsigned short* __restrict__ w1t,
    unsigned short* __restrict__ xb, int* __restrict__ te,
    float* __restrict__ tg) {
  __shared__ unsigned short tT[64][68];
  int bid = blockIdx.x;
  if (bid < 8192) {                       // W1 transpose
    int z = bid >> 10, rem = bid & 1023;
    int c0 = (rem & 63) * 64, r0 = (rem >> 6) * 64;
    transpose_tile(W1 + (size_t)z * DIM * 2 * HID,
                   w1t + (size_t)z * DIM * 2 * HID, DIM, 2 * HID, c0, r0, tT);
  } else {                                // router (4 tokens, 1 wave each)
    int n = (bid - 8192) * 4 + (threadIdx.x >> 6);
    int lane = threadIdx.x & 63;
    float z[8];
#pragma unroll
    for (int e = 0; e < 8; ++e) z[e] = 0.f;
    const float* xr = x + (size_t)n * DIM;
    unsigned short* xbr = xb + (size_t)n * DIM;
#pragma unroll 4
    for (int i = 0; i < DIM / 64; ++i) {
      int d = lane + i * 64;
      float xv = xr[d];
      xbr[d] = f2bf(xv);
      float4 w0 = *(const float4*)(Wr + (size_t)d * 8);
      float4 w1 = *(const float4*)(Wr + (size_t)d * 8 + 4);
      z[0] += xv * w0.x; z[1] += xv * w0.y; z[2] += xv * w0.z; z[3] += xv * w0.w;
      z[4] += xv * w1.x; z[5] += xv * w1.y; z[6] += xv * w1.z; z[7] += xv * w1.w;
    }
    for (int off = 32; off; off >>= 1)
#pragma unroll
      for (int e = 0; e < 8; ++e) z[e] += __shfl_down(z[e], off);
    if (lane == 0) {
      int e0 = 0; float v0 = z[0];
#pragma unroll
      for (int e = 1; e < 8; ++e) if (z[e] > v0) { v0 = z[e]; e0 = e; }
      int e1 = -1; float v1 = -3.4e38f;
#pragma unroll
      for (int e = 0; e < 8; ++e) if (e != e0 && z[e] > v1) { v1 = z[e]; e1 = e; }
      float r = expf(v1 - v0);
      float s0 = 1.f / (1.f + r);
      te[n * 2] = e0; te[n * 2 + 1] = e1;
      tg[n * 2] = s0; tg[n * 2 + 1] = r * s0;
    }
  }
}

// ===== sortscan: one block; histogram -> offs/tl128, scatter ==========
__global__ __launch_bounds__(1024) void sortscan_k(
    const int* __restrict__ te, const float* __restrict__ tg,
    int* __restrict__ offs, int* __restrict__ tl128,
    int* __restrict__ rows, float* __restrict__ rowg) {
  __shared__ int hist[8];
  __shared__ int curs[8];
  int tid = threadIdx.x;
  if (tid < 8) hist[tid] = 0;
  __syncthreads();
  for (int i = tid; i < NK; i += 1024) atomicAdd(&hist[te[i]], 1);
  __syncthreads();
  if (tid == 0) {
    int o = 0, t1 = 0;
    offs[0] = 0; tl128[0] = 0;
    for (int e = 0; e < NEXP; ++e) {
      curs[e] = o;
      o += hist[e];
      offs[e + 1] = o;
      t1 += (hist[e] + 127) >> 7;
      tl128[e + 1] = t1;
    }
  }
  __syncthreads();
  for (int i = tid; i < NK; i += 1024) {
    int e = te[i];
    int pos = atomicAdd(&curs[e], 1);
    rows[pos] = i >> 1;
    rowg[pos] = tg[i];
  }
}

// ==== triple-buffered 2-phase 128x128 grouped GEMM, BK=32, 3 blocks/CU =====
// Per K-step t: vmcnt(4) [lands stage(t); stage(t+1) stays in flight] ->
// barrier -> stage(t+2 -> buf (t+2)%3) -> read buf t%3 -> 16 MFMA.
// Tail: t==NT-1 uses vmcnt(0) (only stage(NT-1) in flight = 4 loads).
template <int GID>
__global__ __launch_bounds__(256, 3) void moe_gemm3b(
    const unsigned short* __restrict__ Asrc,
    const unsigned short* __restrict__ Wt,
    const float* __restrict__ bias,
    unsigned short* __restrict__ hb,
    float* __restrict__ out,
    const int* __restrict__ rows,
    const float* __restrict__ rowg,
    const int* __restrict__ offs,
    const int* __restrict__ tl,
    const float* __restrict__ W2f,       // GID0 aux
    unsigned short* __restrict__ w2td,   // GID0 aux
    float* __restrict__ outz) {          // GID0 aux
  constexpr int KD = (GID == 0) ? DIM : HID;
  constexpr int NT = KD / 32;
  // elements: A bufs [0,12288) (3 x 4096), B bufs [12288,24576)
  __shared__ unsigned short smem[24576];

  int bt = blockIdx.y;
  if (GID == 0 && bt >= MAXT1) {
    if (bt < MAXT1 + 128) {              // W2 transpose, 1 tile/block
      int t = (bt - MAXT1) * 32 + (int)blockIdx.x;   // 0..4095 (gridDim.x=32)
      int z = t >> 9, rem = t & 511;
      int c0 = (rem & 15) * 64, r0 = (rem >> 4) * 64;
      transpose_tile(W2f + (size_t)z * HID * DIM,
                     w2td + (size_t)z * HID * DIM, HID, DIM, c0, r0,
                     (unsigned short(*)[68])smem);
    } else {                             // zero out
      int t = (bt - MAXT1 - 128) * 32 + (int)blockIdx.x;  // 0..255
      float4* o4 = (float4*)outz;
      int idx = t * 256 + threadIdx.x;
#pragma unroll
      for (int i = 0; i < 32; ++i) o4[idx + i * 65536] = (float4){0.f, 0.f, 0.f, 0.f};
    }
    return;
  }
  if (bt >= tl[NEXP]) return;
  int e = 0;
  while (e < NEXP - 1 && bt >= tl[e + 1]) ++e;
  int rt = bt - tl[e];
  int base = offs[e];
  int cntE = offs[e + 1] - base;
  int row0 = rt * 128;
  int jb = blockIdx.x;

  int tid = threadIdx.x, lane = tid & 63, w = tid >> 6;
  int wr = w >> 1, wc = w & 1;

  // ---------- staging (R10 BK=32 swizzle: src granule, linear LDS) ----------
  int g8 = (((lane & 3) ^ ((lane >> 3) & 3)) * 8);
  const unsigned short* aP[2];
  const unsigned short* bP[2];
  int aD[2], bD[2];
#pragma unroll
  for (int s = 0; s < 2; ++s) {
    int rA = w * 16 + (lane >> 2) + s * 64;
    int rr = row0 + rA; rr = rr < cntE ? rr : cntE - 1;
    if (GID == 0) {
      int tok = rows[base + rr];
      aP[s] = Asrc + (size_t)tok * DIM + g8;
    } else {
      aP[s] = Asrc + (size_t)(base + rr) * HID + g8;
    }
    aD[s] = (w * 16 + s * 64) * 32;
    int rB = w * 16 + (lane >> 2) + s * 64;
    if (GID == 0) {
      int j0 = jb * 64;
      int u = rB & 63, wcb = rB >> 6;
      int hcol = j0 + wcb * 32 + (u & 31);
      int w1row = hcol + (u >> 5) * HID;       // +HID for b-half of swiGLU
      bP[s] = Wt + ((size_t)e * 2 * HID + w1row) * DIM + g8;
    } else {
      bP[s] = Wt + ((size_t)e * DIM + (jb * 128 + rB)) * HID + g8;
    }
    bD[s] = (w * 16 + s * 64) * 32;
  }

  auto stg = [&](int t, int buf) {
    if (t < NT) {
      glds16(aP[0] + (size_t)t * 32, smem + buf * 4096 + aD[0]);
      glds16(aP[1] + (size_t)t * 32, smem + buf * 4096 + aD[1]);
      glds16(bP[0] + (size_t)t * 32, smem + 12288 + buf * 4096 + bD[0]);
      glds16(bP[1] + (size_t)t * 32, smem + 12288 + buf * 4096 + bD[1]);
    }
  };

  // ---------- ds_read offsets (R10 swizzle: slot = kg ^ ((r>>1)&3)) ----------
  int kg = lane >> 4, coll = lane & 15;
  int koff = ((kg ^ ((lane >> 1) & 3)) * 8);
  unsigned aoff[4], boff[4];
#pragma unroll
  for (int m = 0; m < 4; ++m) aoff[m] = (unsigned)((wr * 64 + m * 16 + coll) * 32 + koff);
#pragma unroll
  for (int n = 0; n < 4; ++n) boff[n] = (unsigned)((wc * 64 + n * 16 + coll) * 32 + koff);

  f32x4 acc[4][4];
#pragma unroll
  for (int m = 0; m < 4; ++m)
#pragma unroll
    for (int n = 0; n < 4; ++n) acc[m][n] = (f32x4){0.f, 0.f, 0.f, 0.f};

  short8 a[4], b[4];

  // ---------- prologue: stage tiles 0,1 into bufs 0,1 ----------
  stg(0, 0);
  stg(1, 1);

  int rb = 0;
  for (int t = 0; t < NT; ++t) {
    if (t == NT - 1) { VMW0(); } else { VMW4(); }
    FEN(); BARX(); FEN();
    int wb = rb + 2; if (wb >= 3) wb -= 3;
    stg(t + 2, wb);
#pragma unroll
    for (int m = 0; m < 4; ++m)
      a[m] = *(const short8*)(smem + rb * 4096 + aoff[m]);
#pragma unroll
    for (int n = 0; n < 4; ++n)
      b[n] = *(const short8*)(smem + 12288 + rb * 4096 + boff[n]);
    PRIO(1);
#pragma unroll
    for (int m = 0; m < 4; ++m)
#pragma unroll
      for (int n = 0; n < 4; ++n)
        acc[m][n] = __builtin_amdgcn_mfma_f32_16x16x32_bf16(a[m], b[n], acc[m][n], 0, 0, 0);
    PRIO(0);
    rb = (rb + 1 == 3) ? 0 : rb + 1;
  }

  // ---------- epilogue ----------
  int rowl = lane >> 4;
  if (GID == 0) {
    int j0 = jb * 64;
#pragma unroll
    for (int n = 0; n < 2; ++n) {
      int hcol = j0 + wc * 32 + n * 16 + coll;
      float ba = bias[e * 2 * HID + hcol];
      float bb = bias[e * 2 * HID + HID + hcol];
#pragma unroll
      for (int m = 0; m < 4; ++m)
#pragma unroll
        for (int j = 0; j < 4; ++j) {
          int grow = row0 + wr * 64 + m * 16 + rowl * 4 + j;
          if (grow < cntE) {
            float av = acc[m][n][j] + ba;
            float bv = acc[m][n + 2][j] + bb;
            float hv = av / (1.f + __expf(-av)) * bv;
            hb[(size_t)(base + grow) * HID + hcol] = f2bf(hv);
          }
        }
    }
  } else {
#pragma unroll
    for (int m = 0; m < 4; ++m)
#pragma unroll
      for (int j = 0; j < 4; ++j) {
        int grow = row0 + wr * 64 + m * 16 + rowl * 4 + j;
        if (grow < cntE) {
          int tok = rows[base + grow];
          float g = rowg[base + grow];
#pragma unroll
          for (int n = 0; n < 4; ++n) {
            int col = jb * 128 + wc * 64 + n * 16 + coll;
            atomicAdd(&out[(size_t)tok * DIM + col],
                      g * (acc[m][n][j] + bias[e * DIM + col]));
          }
        }
      }
  }
}

extern "C" void kernel_launch(void* const* d_in, const int* in_sizes, int n_in,
                              void* d_out, int out_size, void* d_ws, size_t ws_size,
                              hipStream_t stream) {
  (void)in_sizes; (void)n_in; (void)out_size;
  const float* x  = (const float*)d_in[0];
  const float* Wr = (const float*)d_in[1];
  const float* W1 = (const float*)d_in[2];
  const float* b1 = (const float*)d_in[3];
  const float* W2 = (const float*)d_in[4];
  const float* b2 = (const float*)d_in[5];
  float* out = (float*)d_out;
  char* ws = (char*)d_ws;

  const size_t o_xb   = 0;
  const size_t o_w1t  = o_xb   + (size_t)N_TOK * DIM * 2;
  const size_t o_w2t  = o_w1t  + (size_t)NEXP * 2 * HID * DIM * 2;
  const size_t o_hb   = o_w2t  + (size_t)NEXP * DIM * HID * 2;
  const size_t o_rows = o_hb   + (size_t)NK * HID * 2;
  const size_t o_rowg = o_rows + (size_t)NK * 4;
  const size_t o_te   = o_rowg + (size_t)NK * 4;
  const size_t o_tg   = o_te   + (size_t)NK * 4;
  const size_t o_offs = o_tg   + (size_t)NK * 4;
  const size_t o_t1   = o_offs + 64;
  const size_t need   = o_t1   + 64;
  if (ws_size < need) return;

  unsigned short* xb  = (unsigned short*)(ws + o_xb);
  unsigned short* w1t = (unsigned short*)(ws + o_w1t);
  unsigned short* w2t = (unsigned short*)(ws + o_w2t);
  unsigned short* hb  = (unsigned short*)(ws + o_hb);
  int*   rows = (int*)(ws + o_rows);
  float* rowg = (float*)(ws + o_rowg);
  int*   te   = (int*)(ws + o_te);
  float* tg   = (float*)(ws + o_tg);
  int*   offs = (int*)(ws + o_offs);
  int*   tl128 = (int*)(ws + o_t1);

  prep_k<<<10240, 256, 0, stream>>>(x, Wr, W1, w1t, xb, te, tg);
  sortscan_k<<<1, 1024, 0, stream>>>(te, tg, offs, tl128, rows, rowg);
  moe_gemm3b<0><<<dim3(HID / 64, G1Y), 256, 0, stream>>>(
      xb, w1t, b1, hb, nullptr, rows, rowg, offs, tl128, W2, w2t, out);
  moe_gemm3b<1><<<dim3(DIM / 128, MAXT1), 256, 0, stream>>>(
      hb, w2t, b2, nullptr, out, rows, rowg, offs, tl128, nullptr, nullptr, nullptr);
}

// Round 17
// 393.590 us; speedup vs baseline: 1.0636x; 1.0242x over previous
//
#include <hip/hip_runtime.h>

// MoE top-2/8: routed bf16-MFMA grouped GEMMs.
// R17: hybrid of best-measured parts: gemm1 = R16 3-buffer 128x64h BK=32
// (210us incl. aux W2T+zero); gemm2 = R13 8-phase BM=128 BK=64 (118us).

#define N_TOK 8192
#define DIM   1024
#define HID   2048
#define NEXP  8
#define NK    (N_TOK * 2)
#define MAXT1 136   // max 128-row tiles (128 full + 8 partial)
#define G1Y   272   // gemm1 y: [0,136) tiles, [136,264) W2T, [264,272) zero

typedef __attribute__((ext_vector_type(8))) short short8;
typedef __attribute__((ext_vector_type(4))) float f32x4;

#define BARX() __builtin_amdgcn_s_barrier()
#define FEN()  asm volatile("" ::: "memory")
#define VMW4() asm volatile("s_waitcnt vmcnt(4)" ::: "memory")
#define VMW2() asm volatile("s_waitcnt vmcnt(2)" ::: "memory")
#define VMW0() asm volatile("s_waitcnt vmcnt(0)" ::: "memory")
#define PRIO(p) __builtin_amdgcn_s_setprio(p)

static __device__ __forceinline__ unsigned short f2bf(float f) {
  unsigned int u = __float_as_uint(f);
  u += 0x7fffu + ((u >> 16) & 1u);
  return (unsigned short)(u >> 16);
}

static __device__ __forceinline__ void glds16(const void* g, void* l) {
  __builtin_amdgcn_global_load_lds(
      (const __attribute__((address_space(1))) unsigned int*)g,
      (__attribute__((address_space(3))) unsigned int*)l, 16, 0, 0);
}

// ---- 64x64 transpose-convert tile (256 threads) ----
__device__ __forceinline__ void transpose_tile(const float* __restrict__ s,
                                               unsigned short* __restrict__ d,
                                               int R, int C, int c0, int r0,
                                               unsigned short (*tT)[68]) {
  int tid = threadIdx.x;
  int c = tid & 63, rq = tid >> 6;
#pragma unroll
  for (int q = 0; q < 4; ++q) {
    int rb = q * 16 + rq * 4;
    ushort4 v;
    v.x = f2bf(s[(size_t)(r0 + rb + 0) * C + c0 + c]);
    v.y = f2bf(s[(size_t)(r0 + rb + 1) * C + c0 + c]);
    v.z = f2bf(s[(size_t)(r0 + rb + 2) * C + c0 + c]);
    v.w = f2bf(s[(size_t)(r0 + rb + 3) * C + c0 + c]);
    *(ushort4*)&tT[c][rb] = v;
  }
  __syncthreads();
#pragma unroll
  for (int it = 0; it < 4; ++it) {
    int idx = it * 256 + tid;
    int cc = idx >> 4;
    int r4 = (idx & 15) * 4;
    *(ushort4*)(d + (size_t)(c0 + cc) * R + r0 + r4) = *(const ushort4*)&tT[cc][r4];
  }
}

// ================= prep: W1^T || router (+x->bf16) ================
__global__ __launch_bounds__(256) void prep_k(
    const float* __restrict__ x, const float* __restrict__ Wr,
    const float* __restrict__ W1,
    unsigned short* __restrict__ w1t,
    unsigned short* __restrict__ xb, int* __restrict__ te,
    float* __restrict__ tg) {
  __shared__ unsigned short tT[64][68];
  int bid = blockIdx.x;
  if (bid < 8192) {                       // W1 transpose
    int z = bid >> 10, rem = bid & 1023;
    int c0 = (rem & 63) * 64, r0 = (rem >> 6) * 64;
    transpose_tile(W1 + (size_t)z * DIM * 2 * HID,
                   w1t + (size_t)z * DIM * 2 * HID, DIM, 2 * HID, c0, r0, tT);
  } else {                                // router (4 tokens, 1 wave each)
    int n = (bid - 8192) * 4 + (threadIdx.x >> 6);
    int lane = threadIdx.x & 63;
    float z[8];
#pragma unroll
    for (int e = 0; e < 8; ++e) z[e] = 0.f;
    const float* xr = x + (size_t)n * DIM;
    unsigned short* xbr = xb + (size_t)n * DIM;
#pragma unroll 4
    for (int i = 0; i < DIM / 64; ++i) {
      int d = lane + i * 64;
      float xv = xr[d];
      xbr[d] = f2bf(xv);
      float4 w0 = *(const float4*)(Wr + (size_t)d * 8);
      float4 w1 = *(const float4*)(Wr + (size_t)d * 8 + 4);
      z[0] += xv * w0.x; z[1] += xv * w0.y; z[2] += xv * w0.z; z[3] += xv * w0.w;
      z[4] += xv * w1.x; z[5] += xv * w1.y; z[6] += xv * w1.z; z[7] += xv * w1.w;
    }
    for (int off = 32; off; off >>= 1)
#pragma unroll
      for (int e = 0; e < 8; ++e) z[e] += __shfl_down(z[e], off);
    if (lane == 0) {
      int e0 = 0; float v0 = z[0];
#pragma unroll
      for (int e = 1; e < 8; ++e) if (z[e] > v0) { v0 = z[e]; e0 = e; }
      int e1 = -1; float v1 = -3.4e38f;
#pragma unroll
      for (int e = 0; e < 8; ++e) if (e != e0 && z[e] > v1) { v1 = z[e]; e1 = e; }
      float r = expf(v1 - v0);
      float s0 = 1.f / (1.f + r);
      te[n * 2] = e0; te[n * 2 + 1] = e1;
      tg[n * 2] = s0; tg[n * 2 + 1] = r * s0;
    }
  }
}

// ===== sortscan: one block; histogram -> offs/tl128, scatter ==========
__global__ __launch_bounds__(1024) void sortscan_k(
    const int* __restrict__ te, const float* __restrict__ tg,
    int* __restrict__ offs, int* __restrict__ tl128,
    int* __restrict__ rows, float* __restrict__ rowg) {
  __shared__ int hist[8];
  __shared__ int curs[8];
  int tid = threadIdx.x;
  if (tid < 8) hist[tid] = 0;
  __syncthreads();
  for (int i = tid; i < NK; i += 1024) atomicAdd(&hist[te[i]], 1);
  __syncthreads();
  if (tid == 0) {
    int o = 0, t1 = 0;
    offs[0] = 0; tl128[0] = 0;
    for (int e = 0; e < NEXP; ++e) {
      curs[e] = o;
      o += hist[e];
      offs[e + 1] = o;
      t1 += (hist[e] + 127) >> 7;
      tl128[e + 1] = t1;
    }
  }
  __syncthreads();
  for (int i = tid; i < NK; i += 1024) {
    int e = te[i];
    int pos = atomicAdd(&curs[e], 1);
    rows[pos] = i >> 1;
    rowg[pos] = tg[i];
  }
}

// ==== gemm1: triple-buffered 128x64h grouped GEMM, BK=32, 3 blocks/CU =====
__global__ __launch_bounds__(256, 3) void gemm1_3b(
    const unsigned short* __restrict__ Asrc,
    const unsigned short* __restrict__ Wt,
    const float* __restrict__ bias,
    unsigned short* __restrict__ hb,
    const int* __restrict__ rows,
    const int* __restrict__ offs,
    const int* __restrict__ tl,
    const float* __restrict__ W2f,
    unsigned short* __restrict__ w2td,
    float* __restrict__ outz) {
  constexpr int NT = DIM / 32;
  __shared__ unsigned short smem[24576];

  int bt = blockIdx.y;
  if (bt >= MAXT1) {
    if (bt < MAXT1 + 128) {              // W2 transpose, 1 tile/block
      int t = (bt - MAXT1) * 32 + (int)blockIdx.x;   // 0..4095
      int z = t >> 9, rem = t & 511;
      int c0 = (rem & 15) * 64, r0 = (rem >> 4) * 64;
      transpose_tile(W2f + (size_t)z * HID * DIM,
                     w2td + (size_t)z * HID * DIM, HID, DIM, c0, r0,
                     (unsigned short(*)[68])smem);
    } else {                             // zero out
      int t = (bt - MAXT1 - 128) * 32 + (int)blockIdx.x;  // 0..255
      float4* o4 = (float4*)outz;
      int idx = t * 256 + threadIdx.x;
#pragma unroll
      for (int i = 0; i < 32; ++i) o4[idx + i * 65536] = (float4){0.f, 0.f, 0.f, 0.f};
    }
    return;
  }
  if (bt >= tl[NEXP]) return;
  int e = 0;
  while (e < NEXP - 1 && bt >= tl[e + 1]) ++e;
  int rt = bt - tl[e];
  int base = offs[e];
  int cntE = offs[e + 1] - base;
  int row0 = rt * 128;
  int jb = blockIdx.x;

  int tid = threadIdx.x, lane = tid & 63, w = tid >> 6;
  int wr = w >> 1, wc = w & 1;

  int g8 = (((lane & 3) ^ ((lane >> 3) & 3)) * 8);
  const unsigned short* aP[2];
  const unsigned short* bP[2];
  int aD[2], bD[2];
#pragma unroll
  for (int s = 0; s < 2; ++s) {
    int rA = w * 16 + (lane >> 2) + s * 64;
    int rr = row0 + rA; rr = rr < cntE ? rr : cntE - 1;
    int tok = rows[base + rr];
    aP[s] = Asrc + (size_t)tok * DIM + g8;
    aD[s] = (w * 16 + s * 64) * 32;
    int rB = w * 16 + (lane >> 2) + s * 64;
    int j0 = jb * 64;
    int u = rB & 63, wcb = rB >> 6;
    int hcol = j0 + wcb * 32 + (u & 31);
    int w1row = hcol + (u >> 5) * HID;       // +HID for b-half of swiGLU
    bP[s] = Wt + ((size_t)e * 2 * HID + w1row) * DIM + g8;
    bD[s] = (w * 16 + s * 64) * 32;
  }

  auto stg = [&](int t, int buf) {
    if (t < NT) {
      glds16(aP[0] + (size_t)t * 32, smem + buf * 4096 + aD[0]);
      glds16(aP[1] + (size_t)t * 32, smem + buf * 4096 + aD[1]);
      glds16(bP[0] + (size_t)t * 32, smem + 12288 + buf * 4096 + bD[0]);
      glds16(bP[1] + (size_t)t * 32, smem + 12288 + buf * 4096 + bD[1]);
    }
  };

  int kg = lane >> 4, coll = lane & 15;
  int koff = ((kg ^ ((lane >> 1) & 3)) * 8);
  unsigned aoff[4], boff[4];
#pragma unroll
  for (int m = 0; m < 4; ++m) aoff[m] = (unsigned)((wr * 64 + m * 16 + coll) * 32 + koff);
#pragma unroll
  for (int n = 0; n < 4; ++n) boff[n] = (unsigned)((wc * 64 + n * 16 + coll) * 32 + koff);

  f32x4 acc[4][4];
#pragma unroll
  for (int m = 0; m < 4; ++m)
#pragma unroll
    for (int n = 0; n < 4; ++n) acc[m][n] = (f32x4){0.f, 0.f, 0.f, 0.f};

  short8 a[4], b[4];

  stg(0, 0);
  stg(1, 1);

  int rb = 0;
  for (int t = 0; t < NT; ++t) {
    if (t == NT - 1) { VMW0(); } else { VMW4(); }
    FEN(); BARX(); FEN();
    int wb = rb + 2; if (wb >= 3) wb -= 3;
    stg(t + 2, wb);
#pragma unroll
    for (int m = 0; m < 4; ++m)
      a[m] = *(const short8*)(smem + rb * 4096 + aoff[m]);
#pragma unroll
    for (int n = 0; n < 4; ++n)
      b[n] = *(const short8*)(smem + 12288 + rb * 4096 + boff[n]);
    PRIO(1);
#pragma unroll
    for (int m = 0; m < 4; ++m)
#pragma unroll
      for (int n = 0; n < 4; ++n)
        acc[m][n] = __builtin_amdgcn_mfma_f32_16x16x32_bf16(a[m], b[n], acc[m][n], 0, 0, 0);
    PRIO(0);
    rb = (rb + 1 == 3) ? 0 : rb + 1;
  }

  int rowl = lane >> 4;
  int j0 = jb * 64;
#pragma unroll
  for (int n = 0; n < 2; ++n) {
    int hcol = j0 + wc * 32 + n * 16 + coll;
    float ba = bias[e * 2 * HID + hcol];
    float bb = bias[e * 2 * HID + HID + hcol];
#pragma unroll
    for (int m = 0; m < 4; ++m)
#pragma unroll
      for (int j = 0; j < 4; ++j) {
        int grow = row0 + wr * 64 + m * 16 + rowl * 4 + j;
        if (grow < cntE) {
          float av = acc[m][n][j] + ba;
          float bv = acc[m][n + 2][j] + bb;
          float hv = av / (1.f + __expf(-av)) * bv;
          hb[(size_t)(base + grow) * HID + hcol] = f2bf(hv);
        }
      }
  }
}

// ==== gemm2: R13 8-phase BM=128 BK=64, 512 threads, 96KB LDS ===============
__global__ __launch_bounds__(512, 2) void gemm2_8p(
    const unsigned short* __restrict__ hb,     // [NK][HID]
    const unsigned short* __restrict__ w2t,    // [E][DIM][HID]
    const float* __restrict__ bias,            // b2 [E][DIM]
    float* __restrict__ out,
    const int* __restrict__ rows,
    const float* __restrict__ rowg,
    const int* __restrict__ offs,
    const int* __restrict__ tl) {
  constexpr int NT = HID / 64;
  constexpr int ASZ = 128 * 64;        // 8192 elements
  __shared__ unsigned short smem[2 * ASZ + 2 * 16384];

  int bt = blockIdx.y;
  if (bt >= tl[NEXP]) return;
  int e = 0;
  while (e < NEXP - 1 && bt >= tl[e + 1]) ++e;
  int rt = bt - tl[e];
  int base = offs[e];
  int cntE = offs[e + 1] - base;
  int row0 = rt * 128;
  int jb = blockIdx.x;

  int tid = threadIdx.x, lane = tid & 63, w = tid >> 6;
  int wr = w >> 2, wc = w & 3;

  int g8 = (((lane & 7) ^ ((lane >> 3) & 7)) * 8);
  const unsigned short* aP[2];
  const unsigned short* bP[2][2];
  int aD[2], bD[2][2];
#pragma unroll
  for (int hf = 0; hf < 2; ++hf) {
    {
      int q0 = w * 8;
      int rbA = (q0 < 32 ? q0 : q0 + 32) + hf * 32;
      int rA = rbA + (lane >> 3);
      int rr = row0 + rA; rr = rr < cntE ? rr : cntE - 1;
      aP[hf] = hb + (size_t)(base + rr) * HID + g8;
      aD[hf] = rbA * 64;
    }
#pragma unroll
    for (int s = 0; s < 2; ++s) {
      int q0 = w * 16 + s * 8;
      int rB = hf * 128 + q0 + (lane >> 3);
      int j0 = jb * 256;
      bP[hf][s] = w2t + ((size_t)e * DIM + (j0 + rB)) * HID + g8;
      bD[hf][s] = (hf * 128 + q0) * 64;
    }
  }

  auto stA = [&](int t, int hf) {
    if (t < NT) glds16(aP[hf] + (size_t)t * 64, smem + (t & 1) * ASZ + aD[hf]);
  };
  auto stB = [&](int t, int hf) {
    if (t < NT) {
#pragma unroll
      for (int s = 0; s < 2; ++s)
        glds16(bP[hf][s] + (size_t)t * 64, smem + 2 * ASZ + (t & 1) * 16384 + bD[hf][s]);
    }
  };

  int arow = wr * 64 + (lane & 15);
  int brow = wc * 64 + (lane & 15);
  int kg = lane >> 4, sx = lane & 7;
  unsigned aoffs[2] = {(unsigned)(arow * 64 + ((kg ^ sx) * 8)),
                       (unsigned)(arow * 64 + (((4 + kg) ^ sx) * 8))};
  unsigned boffs[2] = {(unsigned)(brow * 64 + ((kg ^ sx) * 8)),
                       (unsigned)(brow * 64 + (((4 + kg) ^ sx) * 8))};

  f32x4 acc[4][4];
#pragma unroll
  for (int m = 0; m < 4; ++m)
#pragma unroll
    for (int n = 0; n < 4; ++n) acc[m][n] = (f32x4){0.f, 0.f, 0.f, 0.f};

  short8 a[2][2], b[2][4];

#define MFMA_Q(MB, NB)                                                        \
  PRIO(1);                                                                    \
  _Pragma("unroll") for (int ks = 0; ks < 2; ++ks)                            \
  _Pragma("unroll") for (int m = 0; m < 2; ++m)                               \
  _Pragma("unroll") for (int n = 0; n < 2; ++n)                               \
    acc[(MB) + m][(NB) + n] = __builtin_amdgcn_mfma_f32_16x16x32_bf16(        \
        a[ks][m], b[ks][(NB) + n], acc[(MB) + m][(NB) + n], 0, 0, 0);         \
  PRIO(0)

  stA(0, 0); stA(0, 1); stB(0, 0); stB(0, 1); stA(1, 0); stA(1, 1);
  VMW2(); FEN(); BARX(); FEN();

  for (int it = 0; it < NT / 2; ++it) {
    int T = 2 * it;
    bool notlast = (it < NT / 2 - 1);
#pragma unroll
    for (int half = 0; half < 2; ++half) {
      unsigned Ab = half ? (unsigned)ASZ : 0u;
      unsigned Bb = 2u * ASZ + (half ? 16384u : 0u);
      int Tn = T + half;
#pragma unroll
      for (int ks = 0; ks < 2; ++ks) {
#pragma unroll
        for (int m = 0; m < 2; ++m)
          a[ks][m] = *(const short8*)(smem + Ab + aoffs[ks] + m * 1024);
#pragma unroll
        for (int n = 0; n < 2; ++n)
          b[ks][n] = *(const short8*)(smem + Bb + boffs[ks] + n * 1024);
      }
      stB(Tn + 1, 0);
      FEN(); BARX(); FEN();
      MFMA_Q(0, 0);
      FEN(); BARX(); FEN();
#pragma unroll
      for (int ks = 0; ks < 2; ++ks)
#pragma unroll
        for (int n = 2; n < 4; ++n)
          b[ks][n] = *(const short8*)(smem + Bb + boffs[ks] + n * 1024);
      stB(Tn + 1, 1);
      FEN(); BARX(); FEN();
      MFMA_Q(0, 2);
      FEN(); BARX(); FEN();
#pragma unroll
      for (int ks = 0; ks < 2; ++ks)
#pragma unroll
        for (int m = 0; m < 2; ++m)
          a[ks][m] = *(const short8*)(smem + Ab + aoffs[ks] + (2 + m) * 1024);
      stA(Tn + 2, 0);
      FEN(); BARX(); FEN();
      MFMA_Q(2, 2);
      FEN(); BARX(); FEN();
      stA(Tn + 2, 1);
      FEN(); BARX(); FEN();
      MFMA_Q(2, 0);
      if (half == 0) {
        if (notlast) { VMW2(); } else { VMW0(); }
      } else {
        VMW2();
      }
      FEN(); BARX(); FEN();
    }
  }
#undef MFMA_Q

  int rowl = lane >> 4, coll = lane & 15;
  int j0 = jb * 256;
  float bv[4];
#pragma unroll
  for (int n = 0; n < 4; ++n) bv[n] = bias[e * DIM + j0 + wc * 64 + n * 16 + coll];
#pragma unroll
  for (int m = 0; m < 4; ++m)
#pragma unroll
    for (int j = 0; j < 4; ++j) {
      int grow = row0 + wr * 64 + m * 16 + rowl * 4 + j;
      if (grow < cntE) {
        int tok = rows[base + grow];
        float g = rowg[base + grow];
#pragma unroll
        for (int n = 0; n < 4; ++n) {
          int col = j0 + wc * 64 + n * 16 + coll;
          atomicAdd(&out[(size_t)tok * DIM + col], g * (acc[m][n][j] + bv[n]));
        }
      }
    }
}

extern "C" void kernel_launch(void* const* d_in, const int* in_sizes, int n_in,
                              void* d_out, int out_size, void* d_ws, size_t ws_size,
                              hipStream_t stream) {
  (void)in_sizes; (void)n_in; (void)out_size;
  const float* x  = (const float*)d_in[0];
  const float* Wr = (const float*)d_in[1];
  const float* W1 = (const float*)d_in[2];
  const float* b1 = (const float*)d_in[3];
  const float* W2 = (const float*)d_in[4];
  const float* b2 = (const float*)d_in[5];
  float* out = (float*)d_out;
  char* ws = (char*)d_ws;

  const size_t o_xb   = 0;
  const size_t o_w1t  = o_xb   + (size_t)N_TOK * DIM * 2;
  const size_t o_w2t  = o_w1t  + (size_t)NEXP * 2 * HID * DIM * 2;
  const size_t o_hb   = o_w2t  + (size_t)NEXP * DIM * HID * 2;
  const size_t o_rows = o_hb   + (size_t)NK * HID * 2;
  const size_t o_rowg = o_rows + (size_t)NK * 4;
  const size_t o_te   = o_rowg + (size_t)NK * 4;
  const size_t o_tg   = o_te   + (size_t)NK * 4;
  const size_t o_offs = o_tg   + (size_t)NK * 4;
  const size_t o_t1   = o_offs + 64;
  const size_t need   = o_t1   + 64;
  if (ws_size < need) return;

  unsigned short* xb  = (unsigned short*)(ws + o_xb);
  unsigned short* w1t = (unsigned short*)(ws + o_w1t);
  unsigned short* w2t = (unsigned short*)(ws + o_w2t);
  unsigned short* hb  = (unsigned short*)(ws + o_hb);
  int*   rows = (int*)(ws + o_rows);
  float* rowg = (float*)(ws + o_rowg);
  int*   te   = (int*)(ws + o_te);
  float* tg   = (float*)(ws + o_tg);
  int*   offs = (int*)(ws + o_offs);
  int*   tl128 = (int*)(ws + o_t1);

  prep_k<<<10240, 256, 0, stream>>>(x, Wr, W1, w1t, xb, te, tg);
  sortscan_k<<<1, 1024, 0, stream>>>(te, tg, offs, tl128, rows, rowg);
  gemm1_3b<<<dim3(HID / 64, G1Y), 256, 0, stream>>>(
      xb, w1t, b1, hb, rows, offs, tl128, W2, w2t, out);
  gemm2_8p<<<dim3(DIM / 256, MAXT1), 512, 0, stream>>>(
      hb, w2t, b2, out, rows, rowg, offs, tl128);
}

// Round 18
// 389.220 us; speedup vs baseline: 1.0755x; 1.0112x over previous
//
#include <hip/hip_runtime.h>

// MoE top-2/8: routed bf16-MFMA grouped GEMMs.
// R18: R17 + gemm1 K-loop FULLY UNROLLED (NT=32): all staging/ds_read
// addresses fold to compile-time immediates -> kills the ~30% VALUBusy
// address arithmetic that matched MfmaUtil cycle-for-cycle.

#define N_TOK 8192
#define DIM   1024
#define HID   2048
#define NEXP  8
#define NK    (N_TOK * 2)
#define MAXT1 136   // max 128-row tiles (128 full + 8 partial)
#define G1Y   272   // gemm1 y: [0,136) tiles, [136,264) W2T, [264,272) zero

typedef __attribute__((ext_vector_type(8))) short short8;
typedef __attribute__((ext_vector_type(4))) float f32x4;

#define BARX() __builtin_amdgcn_s_barrier()
#define FEN()  asm volatile("" ::: "memory")
#define VMW4() asm volatile("s_waitcnt vmcnt(4)" ::: "memory")
#define VMW2() asm volatile("s_waitcnt vmcnt(2)" ::: "memory")
#define VMW0() asm volatile("s_waitcnt vmcnt(0)" ::: "memory")
#define PRIO(p) __builtin_amdgcn_s_setprio(p)

static __device__ __forceinline__ unsigned short f2bf(float f) {
  unsigned int u = __float_as_uint(f);
  u += 0x7fffu + ((u >> 16) & 1u);
  return (unsigned short)(u >> 16);
}

static __device__ __forceinline__ void glds16(const void* g, void* l) {
  __builtin_amdgcn_global_load_lds(
      (const __attribute__((address_space(1))) unsigned int*)g,
      (__attribute__((address_space(3))) unsigned int*)l, 16, 0, 0);
}

// ---- 64x64 transpose-convert tile (256 threads) ----
__device__ __forceinline__ void transpose_tile(const float* __restrict__ s,
                                               unsigned short* __restrict__ d,
                                               int R, int C, int c0, int r0,
                                               unsigned short (*tT)[68]) {
  int tid = threadIdx.x;
  int c = tid & 63, rq = tid >> 6;
#pragma unroll
  for (int q = 0; q < 4; ++q) {
    int rb = q * 16 + rq * 4;
    ushort4 v;
    v.x = f2bf(s[(size_t)(r0 + rb + 0) * C + c0 + c]);
    v.y = f2bf(s[(size_t)(r0 + rb + 1) * C + c0 + c]);
    v.z = f2bf(s[(size_t)(r0 + rb + 2) * C + c0 + c]);
    v.w = f2bf(s[(size_t)(r0 + rb + 3) * C + c0 + c]);
    *(ushort4*)&tT[c][rb] = v;
  }
  __syncthreads();
#pragma unroll
  for (int it = 0; it < 4; ++it) {
    int idx = it * 256 + tid;
    int cc = idx >> 4;
    int r4 = (idx & 15) * 4;
    *(ushort4*)(d + (size_t)(c0 + cc) * R + r0 + r4) = *(const ushort4*)&tT[cc][r4];
  }
}

// ================= prep: W1^T || router (+x->bf16) ================
__global__ __launch_bounds__(256) void prep_k(
    const float* __restrict__ x, const float* __restrict__ Wr,
    const float* __restrict__ W1,
    unsigned short* __restrict__ w1t,
    unsigned short* __restrict__ xb, int* __restrict__ te,
    float* __restrict__ tg) {
  __shared__ unsigned short tT[64][68];
  int bid = blockIdx.x;
  if (bid < 8192) {                       // W1 transpose
    int z = bid >> 10, rem = bid & 1023;
    int c0 = (rem & 63) * 64, r0 = (rem >> 6) * 64;
    transpose_tile(W1 + (size_t)z * DIM * 2 * HID,
                   w1t + (size_t)z * DIM * 2 * HID, DIM, 2 * HID, c0, r0, tT);
  } else {                                // router (4 tokens, 1 wave each)
    int n = (bid - 8192) * 4 + (threadIdx.x >> 6);
    int lane = threadIdx.x & 63;
    float z[8];
#pragma unroll
    for (int e = 0; e < 8; ++e) z[e] = 0.f;
    const float* xr = x + (size_t)n * DIM;
    unsigned short* xbr = xb + (size_t)n * DIM;
#pragma unroll 4
    for (int i = 0; i < DIM / 64; ++i) {
      int d = lane + i * 64;
      float xv = xr[d];
      xbr[d] = f2bf(xv);
      float4 w0 = *(const float4*)(Wr + (size_t)d * 8);
      float4 w1 = *(const float4*)(Wr + (size_t)d * 8 + 4);
      z[0] += xv * w0.x; z[1] += xv * w0.y; z[2] += xv * w0.z; z[3] += xv * w0.w;
      z[4] += xv * w1.x; z[5] += xv * w1.y; z[6] += xv * w1.z; z[7] += xv * w1.w;
    }
    for (int off = 32; off; off >>= 1)
#pragma unroll
      for (int e = 0; e < 8; ++e) z[e] += __shfl_down(z[e], off);
    if (lane == 0) {
      int e0 = 0; float v0 = z[0];
#pragma unroll
      for (int e = 1; e < 8; ++e) if (z[e] > v0) { v0 = z[e]; e0 = e; }
      int e1 = -1; float v1 = -3.4e38f;
#pragma unroll
      for (int e = 0; e < 8; ++e) if (e != e0 && z[e] > v1) { v1 = z[e]; e1 = e; }
      float r = expf(v1 - v0);
      float s0 = 1.f / (1.f + r);
      te[n * 2] = e0; te[n * 2 + 1] = e1;
      tg[n * 2] = s0; tg[n * 2 + 1] = r * s0;
    }
  }
}

// ===== sortscan: one block; histogram -> offs/tl128, scatter ==========
__global__ __launch_bounds__(1024) void sortscan_k(
    const int* __restrict__ te, const float* __restrict__ tg,
    int* __restrict__ offs, int* __restrict__ tl128,
    int* __restrict__ rows, float* __restrict__ rowg) {
  __shared__ int hist[8];
  __shared__ int curs[8];
  int tid = threadIdx.x;
  if (tid < 8) hist[tid] = 0;
  __syncthreads();
  for (int i = tid; i < NK; i += 1024) atomicAdd(&hist[te[i]], 1);
  __syncthreads();
  if (tid == 0) {
    int o = 0, t1 = 0;
    offs[0] = 0; tl128[0] = 0;
    for (int e = 0; e < NEXP; ++e) {
      curs[e] = o;
      o += hist[e];
      offs[e + 1] = o;
      t1 += (hist[e] + 127) >> 7;
      tl128[e + 1] = t1;
    }
  }
  __syncthreads();
  for (int i = tid; i < NK; i += 1024) {
    int e = te[i];
    int pos = atomicAdd(&curs[e], 1);
    rows[pos] = i >> 1;
    rowg[pos] = tg[i];
  }
}

// ==== gemm1: triple-buffered 128x64h grouped GEMM, BK=32, FULL UNROLL ======
__global__ __launch_bounds__(256, 3) void gemm1_3b(
    const unsigned short* __restrict__ Asrc,
    const unsigned short* __restrict__ Wt,
    const float* __restrict__ bias,
    unsigned short* __restrict__ hb,
    const int* __restrict__ rows,
    const int* __restrict__ offs,
    const int* __restrict__ tl,
    const float* __restrict__ W2f,
    unsigned short* __restrict__ w2td,
    float* __restrict__ outz) {
  constexpr int NT = DIM / 32;          // 32 K-steps
  __shared__ unsigned short smem[24576];

  int bt = blockIdx.y;
  if (bt >= MAXT1) {
    if (bt < MAXT1 + 128) {              // W2 transpose, 1 tile/block
      int t = (bt - MAXT1) * 32 + (int)blockIdx.x;   // 0..4095
      int z = t >> 9, rem = t & 511;
      int c0 = (rem & 15) * 64, r0 = (rem >> 4) * 64;
      transpose_tile(W2f + (size_t)z * HID * DIM,
                     w2td + (size_t)z * HID * DIM, HID, DIM, c0, r0,
                     (unsigned short(*)[68])smem);
    } else {                             // zero out
      int t = (bt - MAXT1 - 128) * 32 + (int)blockIdx.x;  // 0..255
      float4* o4 = (float4*)outz;
      int idx = t * 256 + threadIdx.x;
#pragma unroll
      for (int i = 0; i < 32; ++i) o4[idx + i * 65536] = (float4){0.f, 0.f, 0.f, 0.f};
    }
    return;
  }
  if (bt >= tl[NEXP]) return;
  int e = 0;
  while (e < NEXP - 1 && bt >= tl[e + 1]) ++e;
  int rt = bt - tl[e];
  int base = offs[e];
  int cntE = offs[e + 1] - base;
  int row0 = rt * 128;
  int jb = blockIdx.x;

  int tid = threadIdx.x, lane = tid & 63, w = tid >> 6;
  int wr = w >> 1, wc = w & 1;

  int g8 = (((lane & 3) ^ ((lane >> 3) & 3)) * 8);
  const unsigned short* aP[2];
  const unsigned short* bP[2];
  int aD[2], bD[2];
#pragma unroll
  for (int s = 0; s < 2; ++s) {
    int rA = w * 16 + (lane >> 2) + s * 64;
    int rr = row0 + rA; rr = rr < cntE ? rr : cntE - 1;
    int tok = rows[base + rr];
    aP[s] = Asrc + (size_t)tok * DIM + g8;
    aD[s] = (w * 16 + s * 64) * 32;
    int rB = w * 16 + (lane >> 2) + s * 64;
    int j0 = jb * 64;
    int u = rB & 63, wcb = rB >> 6;
    int hcol = j0 + wcb * 32 + (u & 31);
    int w1row = hcol + (u >> 5) * HID;       // +HID for b-half of swiGLU
    bP[s] = Wt + ((size_t)e * 2 * HID + w1row) * DIM + g8;
    bD[s] = (w * 16 + s * 64) * 32;
  }

  int kg = lane >> 4, coll = lane & 15;
  int koff = ((kg ^ ((lane >> 1) & 3)) * 8);
  unsigned aoff[4], boff[4];
#pragma unroll
  for (int m = 0; m < 4; ++m) aoff[m] = (unsigned)((wr * 64 + m * 16 + coll) * 32 + koff);
#pragma unroll
  for (int n = 0; n < 4; ++n) boff[n] = (unsigned)((wc * 64 + n * 16 + coll) * 32 + koff);

  f32x4 acc[4][4];
#pragma unroll
  for (int m = 0; m < 4; ++m)
#pragma unroll
    for (int n = 0; n < 4; ++n) acc[m][n] = (f32x4){0.f, 0.f, 0.f, 0.f};

  short8 a[4], b[4];

  // prologue: stage tiles 0,1 into bufs 0,1 (compile-time offsets)
  glds16(aP[0], smem + aD[0]);
  glds16(aP[1], smem + aD[1]);
  glds16(bP[0], smem + 12288 + bD[0]);
  glds16(bP[1], smem + 12288 + bD[1]);
  glds16(aP[0] + 32, smem + 4096 + aD[0]);
  glds16(aP[1] + 32, smem + 4096 + aD[1]);
  glds16(bP[0] + 32, smem + 12288 + 4096 + bD[0]);
  glds16(bP[1] + 32, smem + 12288 + 4096 + bD[1]);

#pragma unroll
  for (int t = 0; t < NT; ++t) {
    if (t == NT - 1) { VMW0(); } else { VMW4(); }
    FEN(); BARX(); FEN();
    // stage tile t+2 into buf (t+2)%3 -- all compile-time under full unroll
    if (t + 2 < NT) {
      const int wb = (t + 2) % 3;
      glds16(aP[0] + (t + 2) * 32, smem + wb * 4096 + aD[0]);
      glds16(aP[1] + (t + 2) * 32, smem + wb * 4096 + aD[1]);
      glds16(bP[0] + (t + 2) * 32, smem + 12288 + wb * 4096 + bD[0]);
      glds16(bP[1] + (t + 2) * 32, smem + 12288 + wb * 4096 + bD[1]);
    }
    const int rb = t % 3;
#pragma unroll
    for (int m = 0; m < 4; ++m)
      a[m] = *(const short8*)(smem + rb * 4096 + aoff[m]);
#pragma unroll
    for (int n = 0; n < 4; ++n)
      b[n] = *(const short8*)(smem + 12288 + rb * 4096 + boff[n]);
    PRIO(1);
#pragma unroll
    for (int m = 0; m < 4; ++m)
#pragma unroll
      for (int n = 0; n < 4; ++n)
        acc[m][n] = __builtin_amdgcn_mfma_f32_16x16x32_bf16(a[m], b[n], acc[m][n], 0, 0, 0);
    PRIO(0);
  }

  int rowl = lane >> 4;
  int j0 = jb * 64;
#pragma unroll
  for (int n = 0; n < 2; ++n) {
    int hcol = j0 + wc * 32 + n * 16 + coll;
    float ba = bias[e * 2 * HID + hcol];
    float bb = bias[e * 2 * HID + HID + hcol];
#pragma unroll
    for (int m = 0; m < 4; ++m)
#pragma unroll
      for (int j = 0; j < 4; ++j) {
        int grow = row0 + wr * 64 + m * 16 + rowl * 4 + j;
        if (grow < cntE) {
          float av = acc[m][n][j] + ba;
          float bv = acc[m][n + 2][j] + bb;
          float hv = av / (1.f + __expf(-av)) * bv;
          hb[(size_t)(base + grow) * HID + hcol] = f2bf(hv);
        }
      }
  }
}

// ==== gemm2: R13 8-phase BM=128 BK=64, 512 threads, 96KB LDS ===============
__global__ __launch_bounds__(512, 2) void gemm2_8p(
    const unsigned short* __restrict__ hb,     // [NK][HID]
    const unsigned short* __restrict__ w2t,    // [E][DIM][HID]
    const float* __restrict__ bias,            // b2 [E][DIM]
    float* __restrict__ out,
    const int* __restrict__ rows,
    const float* __restrict__ rowg,
    const int* __restrict__ offs,
    const int* __restrict__ tl) {
  constexpr int NT = HID / 64;
  constexpr int ASZ = 128 * 64;        // 8192 elements
  __shared__ unsigned short smem[2 * ASZ + 2 * 16384];

  int bt = blockIdx.y;
  if (bt >= tl[NEXP]) return;
  int e = 0;
  while (e < NEXP - 1 && bt >= tl[e + 1]) ++e;
  int rt = bt - tl[e];
  int base = offs[e];
  int cntE = offs[e + 1] - base;
  int row0 = rt * 128;
  int jb = blockIdx.x;

  int tid = threadIdx.x, lane = tid & 63, w = tid >> 6;
  int wr = w >> 2, wc = w & 3;

  int g8 = (((lane & 7) ^ ((lane >> 3) & 7)) * 8);
  const unsigned short* aP[2];
  const unsigned short* bP[2][2];
  int aD[2], bD[2][2];
#pragma unroll
  for (int hf = 0; hf < 2; ++hf) {
    {
      int q0 = w * 8;
      int rbA = (q0 < 32 ? q0 : q0 + 32) + hf * 32;
      int rA = rbA + (lane >> 3);
      int rr = row0 + rA; rr = rr < cntE ? rr : cntE - 1;
      aP[hf] = hb + (size_t)(base + rr) * HID + g8;
      aD[hf] = rbA * 64;
    }
#pragma unroll
    for (int s = 0; s < 2; ++s) {
      int q0 = w * 16 + s * 8;
      int rB = hf * 128 + q0 + (lane >> 3);
      int j0 = jb * 256;
      bP[hf][s] = w2t + ((size_t)e * DIM + (j0 + rB)) * HID + g8;
      bD[hf][s] = (hf * 128 + q0) * 64;
    }
  }

  auto stA = [&](int t, int hf) {
    if (t < NT) glds16(aP[hf] + (size_t)t * 64, smem + (t & 1) * ASZ + aD[hf]);
  };
  auto stB = [&](int t, int hf) {
    if (t < NT) {
#pragma unroll
      for (int s = 0; s < 2; ++s)
        glds16(bP[hf][s] + (size_t)t * 64, smem + 2 * ASZ + (t & 1) * 16384 + bD[hf][s]);
    }
  };

  int arow = wr * 64 + (lane & 15);
  int brow = wc * 64 + (lane & 15);
  int kg = lane >> 4, sx = lane & 7;
  unsigned aoffs[2] = {(unsigned)(arow * 64 + ((kg ^ sx) * 8)),
                       (unsigned)(arow * 64 + (((4 + kg) ^ sx) * 8))};
  unsigned boffs[2] = {(unsigned)(brow * 64 + ((kg ^ sx) * 8)),
                       (unsigned)(brow * 64 + (((4 + kg) ^ sx) * 8))};

  f32x4 acc[4][4];
#pragma unroll
  for (int m = 0; m < 4; ++m)
#pragma unroll
    for (int n = 0; n < 4; ++n) acc[m][n] = (f32x4){0.f, 0.f, 0.f, 0.f};

  short8 a[2][2], b[2][4];

#define MFMA_Q(MB, NB)                                                        \
  PRIO(1);                                                                    \
  _Pragma("unroll") for (int ks = 0; ks < 2; ++ks)                            \
  _Pragma("unroll") for (int m = 0; m < 2; ++m)                               \
  _Pragma("unroll") for (int n = 0; n < 2; ++n)                               \
    acc[(MB) + m][(NB) + n] = __builtin_amdgcn_mfma_f32_16x16x32_bf16(        \
        a[ks][m], b[ks][(NB) + n], acc[(MB) + m][(NB) + n], 0, 0, 0);         \
  PRIO(0)

  stA(0, 0); stA(0, 1); stB(0, 0); stB(0, 1); stA(1, 0); stA(1, 1);
  VMW2(); FEN(); BARX(); FEN();

  for (int it = 0; it < NT / 2; ++it) {
    int T = 2 * it;
    bool notlast = (it < NT / 2 - 1);
#pragma unroll
    for (int half = 0; half < 2; ++half) {
      unsigned Ab = half ? (unsigned)ASZ : 0u;
      unsigned Bb = 2u * ASZ + (half ? 16384u : 0u);
      int Tn = T + half;
#pragma unroll
      for (int ks = 0; ks < 2; ++ks) {
#pragma unroll
        for (int m = 0; m < 2; ++m)
          a[ks][m] = *(const short8*)(smem + Ab + aoffs[ks] + m * 1024);
#pragma unroll
        for (int n = 0; n < 2; ++n)
          b[ks][n] = *(const short8*)(smem + Bb + boffs[ks] + n * 1024);
      }
      stB(Tn + 1, 0);
      FEN(); BARX(); FEN();
      MFMA_Q(0, 0);
      FEN(); BARX(); FEN();
#pragma unroll
      for (int ks = 0; ks < 2; ++ks)
#pragma unroll
        for (int n = 2; n < 4; ++n)
          b[ks][n] = *(const short8*)(smem + Bb + boffs[ks] + n * 1024);
      stB(Tn + 1, 1);
      FEN(); BARX(); FEN();
      MFMA_Q(0, 2);
      FEN(); BARX(); FEN();
#pragma unroll
      for (int ks = 0; ks < 2; ++ks)
#pragma unroll
        for (int m = 0; m < 2; ++m)
          a[ks][m] = *(const short8*)(smem + Ab + aoffs[ks] + (2 + m) * 1024);
      stA(Tn + 2, 0);
      FEN(); BARX(); FEN();
      MFMA_Q(2, 2);
      FEN(); BARX(); FEN();
      stA(Tn + 2, 1);
      FEN(); BARX(); FEN();
      MFMA_Q(2, 0);
      if (half == 0) {
        if (notlast) { VMW2(); } else { VMW0(); }
      } else {
        VMW2();
      }
      FEN(); BARX(); FEN();
    }
  }
#undef MFMA_Q

  int rowl = lane >> 4, coll = lane & 15;
  int j0 = jb * 256;
  float bv[4];
#pragma unroll
  for (int n = 0; n < 4; ++n) bv[n] = bias[e * DIM + j0 + wc * 64 + n * 16 + coll];
#pragma unroll
  for (int m = 0; m < 4; ++m)
#pragma unroll
    for (int j = 0; j < 4; ++j) {
      int grow = row0 + wr * 64 + m * 16 + rowl * 4 + j;
      if (grow < cntE) {
        int tok = rows[base + grow];
        float g = rowg[base + grow];
#pragma unroll
        for (int n = 0; n < 4; ++n) {
          int col = j0 + wc * 64 + n * 16 + coll;
          atomicAdd(&out[(size_t)tok * DIM + col], g * (acc[m][n][j] + bv[n]));
        }
      }
    }
}

extern "C" void kernel_launch(void* const* d_in, const int* in_sizes, int n_in,
                              void* d_out, int out_size, void* d_ws, size_t ws_size,
                              hipStream_t stream) {
  (void)in_sizes; (void)n_in; (void)out_size;
  const float* x  = (const float*)d_in[0];
  const float* Wr = (const float*)d_in[1];
  const float* W1 = (const float*)d_in[2];
  const float* b1 = (const float*)d_in[3];
  const float* W2 = (const float*)d_in[4];
  const float* b2 = (const float*)d_in[5];
  float* out = (float*)d_out;
  char* ws = (char*)d_ws;

  const size_t o_xb   = 0;
  const size_t o_w1t  = o_xb   + (size_t)N_TOK * DIM * 2;
  const size_t o_w2t  = o_w1t  + (size_t)NEXP * 2 * HID * DIM * 2;
  const size_t o_hb   = o_w2t  + (size_t)NEXP * DIM * HID * 2;
  const size_t o_rows = o_hb   + (size_t)NK * HID * 2;
  const size_t o_rowg = o_rows + (size_t)NK * 4;
  const size_t o_te   = o_rowg + (size_t)NK * 4;
  const size_t o_tg   = o_te   + (size_t)NK * 4;
  const size_t o_offs = o_tg   + (size_t)NK * 4;
  const size_t o_t1   = o_offs + 64;
  const size_t need   = o_t1   + 64;
  if (ws_size < need) return;

  unsigned short* xb  = (unsigned short*)(ws + o_xb);
  unsigned short* w1t = (unsigned short*)(ws + o_w1t);
  unsigned short* w2t = (unsigned short*)(ws + o_w2t);
  unsigned short* hb  = (unsigned short*)(ws + o_hb);
  int*   rows = (int*)(ws + o_rows);
  float* rowg = (float*)(ws + o_rowg);
  int*   te   = (int*)(ws + o_te);
  float* tg   = (float*)(ws + o_tg);
  int*   offs = (int*)(ws + o_offs);
  int*   tl128 = (int*)(ws + o_t1);

  prep_k<<<10240, 256, 0, stream>>>(x, Wr, W1, w1t, xb, te, tg);
  sortscan_k<<<1, 1024, 0, stream>>>(te, tg, offs, tl128, rows, rowg);
  gemm1_3b<<<dim3(HID / 64, G1Y), 256, 0, stream>>>(
      xb, w1t, b1, hb, rows, offs, tl128, W2, w2t, out);
  gemm2_8p<<<dim3(DIM / 256, MAXT1), 512, 0, stream>>>(
      hb, w2t, b2, out, rows, rowg, offs, tl128);
}